// Round 3
// baseline (214.135 us; speedup 1.0000x reference)
//
#include <hip/hip_runtime.h>

// TopKActivation: out = relu(x) masked to the row-wise top-k of relu(x).
// [16384 x 4096] fp32, k=64. One 256-thread block per row-slice; persistent
// blocks (1024) each process 16 rows, software-pipelined: next row's loads are
// issued before the current row's threshold select and stay in flight across
// LDS-only barriers (s_waitcnt lgkmcnt(0) + raw s_barrier — no vmcnt drain).
//
// Threshold: candidates > 1.5f are compacted into LDS (~274 of 4096 for
// N(0,1)); wave 0 alone runs a 4x8-bit MSB radix select on the compacted list
// (positive floats order as uints). Exact full-block fallback if the guarded
// prefilter fails (cnt < k or cnt > CAP). Ties at the threshold resolved
// stably (lowest column index first) to match XLA top_k.

constexpr int ROW_LEN = 4096;
constexpr int TPB     = 256;
constexpr int EPT     = ROW_LEN / TPB; // 16 elements per thread
constexpr int CAP     = 512;           // compacted-candidate capacity
constexpr unsigned int KPRE_BITS = 0x3FC00000u; // bits of 1.5f

typedef float f32x4 __attribute__((ext_vector_type(4))); // native vec: NT builtins accept it

// LDS-only barrier: orders LDS producer->consumer without draining vmcnt,
// so prefetched global loads stay in flight across the select phase.
__device__ __forceinline__ void bar_lds() {
    asm volatile("s_waitcnt lgkmcnt(0)" ::: "memory");
    __builtin_amdgcn_sched_barrier(0);
    __builtin_amdgcn_s_barrier();
}

__global__ __launch_bounds__(TPB, 4)
void topk_relu_kernel(const float* __restrict__ x, const int* __restrict__ kptr,
                      float* __restrict__ out, int rows)
{
    __shared__ unsigned int cand[CAP];
    __shared__ alignas(16) int hist[256];
    __shared__ int ccount;
    __shared__ unsigned int selT;
    __shared__ int selNeed;
    __shared__ int wtot[4];
    __shared__ int sel_digit, sel_kk, sel_flag;

    const int tid  = threadIdx.x;
    const int lane = tid & 63;
    const int wid  = tid >> 6;

    int k = *kptr;
    if (k > ROW_LEN) k = ROW_LEN;

    int row = blockIdx.x;
    const int stride = gridDim.x;
    if (row >= rows) return;

    // ---- load first row (blocked: thread t owns cols [16t,16t+16)) ----
    unsigned int key[EPT];
    {
        const f32x4* __restrict__ xv =
            (const f32x4*)(x + (size_t)row * ROW_LEN + (size_t)tid * EPT);
#pragma unroll
        for (int j = 0; j < 4; ++j) {
            f32x4 v = __builtin_nontemporal_load(&xv[j]);
#pragma unroll
            for (int c = 0; c < 4; ++c)
                key[4 * j + c] = __float_as_uint(fmaxf(v[c], 0.0f));
        }
    }

    for (;;) {
        const int nrow = row + stride;
        const bool haveNext = (nrow < rows);

        // ---- issue next row's loads NOW; they stay in flight through select ----
        f32x4 pf[4];
        if (haveNext) {
            const f32x4* __restrict__ xv =
                (const f32x4*)(x + (size_t)nrow * ROW_LEN + (size_t)tid * EPT);
#pragma unroll
            for (int j = 0; j < 4; ++j) pf[j] = __builtin_nontemporal_load(&xv[j]);
        }

        if (tid == 0) { ccount = 0; sel_flag = 0; }
        bar_lds();

        // ---- compact candidates > 1.5f into LDS ----
        int m = 0;
#pragma unroll
        for (int j = 0; j < EPT; ++j) m += (key[j] > KPRE_BITS) ? 1 : 0;
        int inc = m;
#pragma unroll
        for (int d = 1; d < 64; d <<= 1) {
            int v = __shfl_up(inc, d);
            if (lane >= d) inc += v;
        }
        const int excl = inc - m;          // exclusive prefix within wave
        const int wt   = __shfl(inc, 63);  // wave total
        int wb = 0;
        if (lane == 0) wb = atomicAdd(&ccount, wt);
        wb = __shfl(wb, 0);
        int pos = wb + excl;
#pragma unroll
        for (int j = 0; j < EPT; ++j) {
            if (key[j] > KPRE_BITS) {
                if (pos < CAP) cand[pos] = key[j];
                ++pos;
            }
        }
        bar_lds();
        const int cnt = ccount;

        unsigned int T;
        int need;

        if (cnt >= k && cnt <= CAP) {
            // ---- fast select: wave 0 only, no intra-pass barriers ----
            if (wid == 0) {
                unsigned int c[CAP / 64];
#pragma unroll
                for (int i = 0; i < CAP / 64; ++i) {
                    const int idx = lane + 64 * i;
                    c[i] = (idx < cnt) ? cand[idx] : 0u;
                }
                int kk = k;
                unsigned int prefix = 0;
#pragma unroll
                for (int p = 0; p < 4; ++p) {
                    const int shift = 24 - 8 * p;
                    ((int4*)hist)[lane] = make_int4(0, 0, 0, 0);
#pragma unroll
                    for (int i = 0; i < CAP / 64; ++i) {
                        const int idx = lane + 64 * i;
                        const unsigned int ci = c[i];
                        if (idx < cnt && (p == 0 || (ci >> (shift + 8)) == prefix))
                            atomicAdd(&hist[(ci >> shift) & 255u], 1);
                    }
                    const int4 h = ((const int4*)hist)[lane];
                    const int h0 = h.x, h1 = h.y, h2 = h.z, h3 = h.w;
                    const int lsum = h0 + h1 + h2 + h3;
                    int suf = lsum; // inclusive suffix sum across lanes
#pragma unroll
                    for (int d = 1; d < 64; d <<= 1) {
                        int v = __shfl_down(suf, d);
                        if (lane < 64 - d) suf += v;
                    }
                    const unsigned long long mm = __ballot(suf >= kk); // nonzero: cnt>=kk
                    const int L = 63 - __clzll(mm);
                    int dig = 0, kkn = 0;
                    if (lane == L) {
                        int cum = suf - lsum; // keys strictly above this lane's bins
                        const int hh[4] = {h0, h1, h2, h3};
#pragma unroll
                        for (int b = 3; b >= 0; --b) {
                            if (cum + hh[b] >= kk) { dig = lane * 4 + b; kkn = kk - cum; break; }
                            cum += hh[b];
                        }
                    }
                    dig = __shfl(dig, L);
                    kk  = __shfl(kkn, L);
                    prefix = (prefix << 8) | (unsigned int)dig;
                }
                if (lane == 0) { selT = prefix; selNeed = kk; }
            }
            bar_lds();
            T = selT;
            need = selNeed;
        } else {
            // ---- exact fallback: full-block 4-pass histogram over all positives ----
            int kk = k;
            unsigned int prefix = 0;
            int t0 = 0;
            for (int p = 0; p < 4; ++p) {
                const int shift = 24 - 8 * p;
                hist[tid] = 0;
                if (tid == 0) sel_flag = 0;
                bar_lds();
#pragma unroll
                for (int j = 0; j < EPT; ++j) {
                    const unsigned int kj = key[j];
                    if (kj != 0u && (p == 0 || (kj >> (shift + 8)) == prefix))
                        atomicAdd(&hist[(kj >> shift) & 255u], 1);
                }
                bar_lds();
                if (tid < 64) {
                    const int b0 = tid * 4;
                    const int h0 = hist[b0 + 0], h1 = hist[b0 + 1];
                    const int h2 = hist[b0 + 2], h3 = hist[b0 + 3];
                    const int lsum = h0 + h1 + h2 + h3;
                    int suf = lsum;
#pragma unroll
                    for (int d = 1; d < 64; d <<= 1) {
                        int v = __shfl_down(suf, d);
                        if (lane < 64 - d) suf += v;
                    }
                    const unsigned long long mm = __ballot(suf >= kk);
                    if (mm == 0ull) {
                        if (lane == 0) sel_flag = 1;
                    } else {
                        const int L = 63 - __clzll(mm);
                        if (lane == L) {
                            int cum = suf - lsum;
                            const int hh[4] = {h0, h1, h2, h3};
#pragma unroll
                            for (int b = 3; b >= 0; --b) {
                                if (cum + hh[b] >= kk) { sel_digit = b0 + b; sel_kk = kk - cum; break; }
                                cum += hh[b];
                            }
                        }
                    }
                }
                bar_lds();
                if (sel_flag) { t0 = 1; break; }
                prefix = (prefix << 8) | (unsigned int)sel_digit;
                kk = sel_kk;
                bar_lds(); // protect sel_* from next pass's re-init
            }
            if (t0) { T = 0u; need = 0; }
            else    { T = prefix; need = kk; }
        }

        // ---- stable rank of ==T elements in ascending column order ----
        int eqc = 0;
#pragma unroll
        for (int j = 0; j < EPT; ++j) eqc += (key[j] == T) ? 1 : 0;
        int einc = eqc;
#pragma unroll
        for (int d = 1; d < 64; d <<= 1) {
            int v = __shfl_up(einc, d);
            if (lane >= d) einc += v;
        }
        if (lane == 63) wtot[wid] = einc;
        bar_lds();
        int rbase = 0;
        for (int w = 0; w < wid; ++w) rbase += wtot[w];
        int rr = rbase + (einc - eqc);

        // ---- emit ----
        f32x4* __restrict__ ov = (f32x4*)(out + (size_t)row * ROW_LEN + (size_t)tid * EPT);
#pragma unroll
        for (int j = 0; j < 4; ++j) {
            f32x4 v;
#pragma unroll
            for (int c2 = 0; c2 < 4; ++c2) {
                const unsigned int kj = key[4 * j + c2];
                const bool eq = (kj == T);
                const bool keep = (kj > T) || (eq && rr < need);
                v[c2] = keep ? __uint_as_float(kj) : 0.0f;
                rr += eq ? 1 : 0;
            }
            __builtin_nontemporal_store(v, &ov[j]);
        }

        if (!haveNext) break;
        row = nrow;
        // ---- consume prefetched row (vmcnt wait lands here) ----
#pragma unroll
        for (int j = 0; j < 4; ++j) {
#pragma unroll
            for (int c = 0; c < 4; ++c)
                key[4 * j + c] = __float_as_uint(fmaxf(pf[j][c], 0.0f));
        }
    }
}

extern "C" void kernel_launch(void* const* d_in, const int* in_sizes, int n_in,
                              void* d_out, int out_size, void* d_ws, size_t ws_size,
                              hipStream_t stream)
{
    const float* x    = (const float*)d_in[0];
    const int*   kptr = (const int*)d_in[1];
    float*       out  = (float*)d_out;
    const int rows = in_sizes[0] / ROW_LEN;
    int nb = rows < 1024 ? rows : 1024;
    topk_relu_kernel<<<nb, TPB, 0, stream>>>(x, kptr, out, rows);
}